// Round 3
// baseline (29.327 us; speedup 1.0000x reference)
//
#include <hip/hip_runtime.h>

#define N_SRC 16
#define BATCH 8192
#define FEAT 256
#define SLICE_LEN 128

// 4-byte-aligned float4 load (HW-supported unaligned dwordx4 on gfx950).
typedef float f4u __attribute__((ext_vector_type(4), aligned(4)));

// out[b, n*128 + j] = src[n, b, starts[n] + j]
// Each thread handles TWO float4s in two wave-contiguous output segments
// (segment stride = blockDim*4 floats), giving MLP=2 with perfectly
// coalesced per-instruction access. Stores are nontemporal: output is
// never re-read by this kernel, keep it from churning L2/L3 so the read
// stream can stay cache-resident across timed replays.
__global__ __launch_bounds__(256)
void FusedSliceCat_kernel(const float* __restrict__ src,
                          const int* __restrict__ slice_params,
                          float* __restrict__ out) {
    __shared__ int s_start[N_SRC];
    if (threadIdx.x < N_SRC) s_start[threadIdx.x] = slice_params[2 * threadIdx.x];
    __syncthreads();

    // Block covers 2048 floats (one full output row's worth per block pair);
    // two segments of 1024 floats each.
    int base = blockIdx.x * 2048 + (threadIdx.x << 2);

#pragma unroll
    for (int seg = 0; seg < 2; ++seg) {
        int o   = base + seg * 1024;   // output float index (multiple of 4)
        int b   = o >> 11;
        int rem = o & 2047;
        int n   = rem >> 7;
        int j   = rem & 127;

        const float* s = src + (((size_t)n * BATCH + b) * FEAT + s_start[n] + j);
        f4u v = *reinterpret_cast<const f4u*>(s);
        __builtin_nontemporal_store(v.x, out + o + 0);
        __builtin_nontemporal_store(v.y, out + o + 1);
        __builtin_nontemporal_store(v.z, out + o + 2);
        __builtin_nontemporal_store(v.w, out + o + 3);
    }
}

extern "C" void kernel_launch(void* const* d_in, const int* in_sizes, int n_in,
                              void* d_out, int out_size, void* d_ws, size_t ws_size,
                              hipStream_t stream) {
    const float* src          = (const float*)d_in[0];
    const int*   slice_params = (const int*)d_in[1];
    float*       out          = (float*)d_out;

    const int total = BATCH * N_SRC * SLICE_LEN;   // 16,777,216 floats
    const int grid  = total / 2048;                // 8192 blocks, 256 thr each

    FusedSliceCat_kernel<<<grid, 256, 0, stream>>>(src, slice_params, out);
}

// Round 4
// 26.973 us; speedup vs baseline: 1.0873x; 1.0873x over previous
//
#include <hip/hip_runtime.h>

#define N_SRC 16
#define BATCH 8192
#define FEAT 256
#define SLICE_LEN 128

// 4-byte-aligned float4 load (HW-supported unaligned dwordx4 on gfx950).
typedef float f4u __attribute__((ext_vector_type(4), aligned(4)));
typedef float f4a __attribute__((ext_vector_type(4), aligned(16)));

// out[b, n*128 + j] = src[n, b, starts[n] + j]
// Exact R1 structure (best so far: 27.14us). ONE decoupled change: the
// store is a single nontemporal dwordx4 — tests whether keeping the
// 64MB write stream out of L3 lets the 80MB read-line set stay
// L3-resident across timed replays (total footprint 144MiB < 256MiB L3).
__global__ __launch_bounds__(256)
void FusedSliceCat_kernel(const float* __restrict__ src,
                          const int* __restrict__ slice_params,
                          float* __restrict__ out) {
    __shared__ int s_start[N_SRC];
    if (threadIdx.x < N_SRC) s_start[threadIdx.x] = slice_params[2 * threadIdx.x];
    __syncthreads();

    int t = blockIdx.x * blockDim.x + threadIdx.x;   // grid sized exactly

    int o   = t << 2;          // output float index (multiple of 4)
    int b   = o >> 11;         // / 2048
    int rem = o & 2047;
    int n   = rem >> 7;        // which source
    int j   = rem & 127;       // position within slice (multiple of 4)

    const float* s = src + (((size_t)n * BATCH + b) * FEAT + s_start[n] + j);
    f4u v = *reinterpret_cast<const f4u*>(s);        // 1x dwordx4, 4B-aligned
    __builtin_nontemporal_store(v, reinterpret_cast<f4a*>(out + o));  // 1x dwordx4 nt
}

extern "C" void kernel_launch(void* const* d_in, const int* in_sizes, int n_in,
                              void* d_out, int out_size, void* d_ws, size_t ws_size,
                              hipStream_t stream) {
    const float* src          = (const float*)d_in[0];
    const int*   slice_params = (const int*)d_in[1];
    float*       out          = (float*)d_out;

    const int total  = BATCH * N_SRC * SLICE_LEN;  // 16,777,216 floats
    const int total4 = total / 4;                  // 4,194,304 threads
    const int block  = 256;
    const int grid   = total4 / block;             // exact: 16384

    FusedSliceCat_kernel<<<grid, block, 0, stream>>>(src, slice_params, out);
}